// Round 8
// baseline (699.615 us; speedup 1.0000x reference)
//
#include <hip/hip_runtime.h>
#include <cstdint>
#include <cstddef>

#define DEV __device__ __forceinline__

typedef _Float16 f16;
typedef __attribute__((ext_vector_type(8))) _Float16 f16x8;
typedef __attribute__((ext_vector_type(4))) float f32x4;
typedef __attribute__((ext_vector_type(4))) unsigned short us4;

DEV unsigned short f2h(float f) {
  f16 h = (f16)f;
  return __builtin_bit_cast(unsigned short, h);
}

DEV void async_ld16(const void* g, void* l) {
  __builtin_amdgcn_global_load_lds(
      (__attribute__((address_space(1))) unsigned int*)(uintptr_t)g,
      (__attribute__((address_space(3))) unsigned int*)(uint32_t)(uintptr_t)l,
      16, 0, 0);
}

#define MFMA16(d, a, b_) (d) = __builtin_amdgcn_mfma_f32_16x16x32_f16((a), (b_), (d), 0, 0, 0)

// ---------------------------------------------------------------------------
// gemm256: C[M x N] = A[M x K] * B[N x K]^T  (K-contiguous, f16-as-ushort)
// 256xBN tile (BN in {256,192}), BK=64, 8 waves (2Mx4N), 8-phase pipeline
// (schedule verified R1-R3; BN=192 verified R5). Unchanged since R7.
// EPI: 0 = fp16 store (+bias/relu), 1 = fp32 shard store at Cp + zb*Mtot*ldc,
//      2 = fp32 atomicAdd (legacy).
// ---------------------------------------------------------------------------
template <int BN, int EPI, bool RELU, bool HASBIAS, bool ALPHA, bool XCD>
__global__ __launch_bounds__(512, 2) void gemm256(
    const unsigned short* __restrict__ A, const unsigned short* __restrict__ B,
    void* __restrict__ Cp, const float* __restrict__ bias,
    const unsigned short* __restrict__ alp, int Mtot,
    int K, int lda, int ldb, int ldc, int nt, int mt, int sl) {
  extern __shared__ char smem[];
  constexpr int FN = BN / 64;
  constexpr int WCW = BN / 4;
  constexpr int BUFSZ = 32768 + BN * 128;
  const int NT = K >> 6;

  int mb, nb, zb;
  {
    const int b = blockIdx.x;
    if (XCD) {
      const int xcd = b & 7, q = b >> 3;
      nb = q % nt;
      const int rest = q / nt;
      zb = rest % sl;
      mb = xcd * (mt >> 3) + rest / sl;
    } else {
      nb = b % nt;
      const int t = b / nt;
      mb = t % mt;
      zb = t / mt;
    }
  }
  const int bm = mb << 8, bn = nb * BN;
  const unsigned koff = (unsigned)zb * (unsigned)K;

  const int tid = threadIdx.x;
  const int wave = tid >> 6, lane = tid & 63;
  const int wr = wave >> 2, wc = wave & 3;
  const int mr = lane & 15, quad = lane >> 4;

  const int slot = tid & 7, rr = tid >> 3;
  const int ce = (slot ^ (rr & 7)) << 3;

  f32x4 acc[8][FN] = {};
  f16x8 av0[4][2], av1[4][2], bv0[2][2], bv1[FN - 2][2];
  const f16* alb = (const f16*)(smem + 2 * BUFSZ);

  if (ALPHA) {
    const int ntl = K >> 7;
    const unsigned short* g0 = alp + (size_t)(zb * ntl) * Mtot + bm;
    uint4* s = (uint4*)(smem + 2 * BUFSZ);
    const int nu4 = (ntl << 5);
    for (int idx = tid; idx < nu4; idx += 512) {
      const int tt = idx >> 5;
      const int ru = (idx & 31) << 3;
      s[idx] = *(const uint4*)(g0 + (size_t)tt * Mtot + ru);
    }
  }

  auto stA = [&](int h, int Ts) {
    const int t_ = Ts >= NT ? Ts - NT : Ts;
    const unsigned kk = koff + (unsigned)(t_ << 6);
    char* l = smem + (Ts & 1) * BUFSZ + h * 16384 + wave * 1024;
#pragma unroll
    for (int p = 0; p < 2; ++p) {
      const unsigned off = (unsigned)(bm + p * 128 + h * 64 + rr) * (unsigned)lda + kk + ce;
      async_ld16(A + off, l + p * 8192);
    }
  };
  auto stB = [&](int h, int Ts) {
    const int t_ = Ts >= NT ? Ts - NT : Ts;
    const unsigned kk = koff + (unsigned)(t_ << 6);
    char* l = smem + (Ts & 1) * BUFSZ + 32768 + h * 16384 + wave * 1024;
    if (BN == 256) {
#pragma unroll
      for (int p = 0; p < 2; ++p) {
        const int g = bn + p * 128 + (rr >> 5) * 64 + h * 32 + (rr & 31);
        async_ld16(B + ((unsigned)g * (unsigned)ldb + kk + ce), l + p * 8192);
      }
    } else if (h == 0) {
#pragma unroll
      for (int p = 0; p < 2; ++p) {
        const int g = bn + (p * 2 + (rr >> 5)) * 48 + (rr & 31);
        async_ld16(B + ((unsigned)g * (unsigned)ldb + kk + ce), l + p * 8192);
      }
    } else {
      const int g = bn + (rr >> 4) * 48 + 32 + (rr & 15);
      async_ld16(B + ((unsigned)g * (unsigned)ldb + kk + ce), l);
    }
  };
  auto rdA = [&](int bufc, int i, int ks) {
    const int r = wr * 64 + (i & 3) * 16 + mr;
    return *(const f16x8*)(smem + bufc + (i >> 2) * 16384 + r * 128 +
                           ((((ks << 2) | quad) ^ (mr & 7)) << 4));
  };
  auto rdB0 = [&](int bufc, int j, int ks) {
    const int rb = wc * 32 + j * 16 + mr;
    return *(const f16x8*)(smem + bufc + 32768 + rb * 128 +
                           ((((ks << 2) | quad) ^ (mr & 7)) << 4));
  };
  auto rdB1 = [&](int bufc, int j, int ks) {
    const int rb = (BN == 256) ? (wc * 32 + (j - 2) * 16 + mr) : (wc * 16 + mr);
    return *(const f16x8*)(smem + bufc + 32768 + 16384 + rb * 128 +
                           ((((ks << 2) | quad) ^ (mr & 7)) << 4));
  };

  stA(0, 0); stB(0, 0); stA(1, 0); stB(1, 0);
  stA(0, 1); stB(0, 1); stA(1, 1);
  if (ALPHA) asm volatile("s_waitcnt lgkmcnt(0)" ::: "memory");
  asm volatile("s_waitcnt vmcnt(6)" ::: "memory");
  __builtin_amdgcn_s_barrier();

  for (int T = 0; T < NT; ++T) {
    const int bufc = (T & 1) * BUFSZ;
    f16 a0_[4], a1_[4];
#pragma unroll
    for (int i = 0; i < 4; ++i) { av0[i][0] = rdA(bufc, i, 0); av0[i][1] = rdA(bufc, i, 1); }
    if (ALPHA) {
#pragma unroll
      for (int i = 0; i < 4; ++i) a0_[i] = alb[(T >> 1) * 256 + wr * 128 + i * 16 + mr];
    }
    stB(1, T + 1);
    __builtin_amdgcn_s_barrier();
    asm volatile("s_waitcnt lgkmcnt(0)" ::: "memory");
    __builtin_amdgcn_sched_barrier(0);
    if (ALPHA) {
#pragma unroll
      for (int i = 0; i < 4; ++i) { av0[i][0] = av0[i][0] * a0_[i]; av0[i][1] = av0[i][1] * a0_[i]; }
    }
    if (T) {
      __builtin_amdgcn_s_setprio(1);
#pragma unroll
      for (int i = 0; i < 4; ++i)
#pragma unroll
        for (int j = 0; j < FN - 2; ++j) {
          MFMA16(acc[4 + i][2 + j], av1[i][0], bv1[j][0]);
          MFMA16(acc[4 + i][2 + j], av1[i][1], bv1[j][1]);
        }
      __builtin_amdgcn_s_setprio(0);
    }
    __builtin_amdgcn_s_barrier();
#pragma unroll
    for (int j = 0; j < 2; ++j) { bv0[j][0] = rdB0(bufc, j, 0); bv0[j][1] = rdB0(bufc, j, 1); }
    stA(0, T + 2);
    __builtin_amdgcn_s_barrier();
    asm volatile("s_waitcnt lgkmcnt(0)" ::: "memory");
    __builtin_amdgcn_sched_barrier(0);
    __builtin_amdgcn_s_setprio(1);
#pragma unroll
    for (int i = 0; i < 4; ++i)
#pragma unroll
      for (int j = 0; j < 2; ++j) {
        MFMA16(acc[i][j], av0[i][0], bv0[j][0]);
        MFMA16(acc[i][j], av0[i][1], bv0[j][1]);
      }
    __builtin_amdgcn_s_setprio(0);
    __builtin_amdgcn_s_barrier();
#pragma unroll
    for (int i = 0; i < 4; ++i) { av1[i][0] = rdA(bufc, 4 + i, 0); av1[i][1] = rdA(bufc, 4 + i, 1); }
    if (ALPHA) {
#pragma unroll
      for (int i = 0; i < 4; ++i) a1_[i] = alb[(T >> 1) * 256 + wr * 128 + 64 + i * 16 + mr];
    }
    stB(0, T + 2);
    __builtin_amdgcn_s_barrier();
    asm volatile("s_waitcnt lgkmcnt(0)" ::: "memory");
    __builtin_amdgcn_sched_barrier(0);
    if (ALPHA) {
#pragma unroll
      for (int i = 0; i < 4; ++i) { av1[i][0] = av1[i][0] * a1_[i]; av1[i][1] = av1[i][1] * a1_[i]; }
    }
    __builtin_amdgcn_s_setprio(1);
#pragma unroll
    for (int i = 0; i < 4; ++i)
#pragma unroll
      for (int j = 0; j < 2; ++j) {
        MFMA16(acc[4 + i][j], av1[i][0], bv0[j][0]);
        MFMA16(acc[4 + i][j], av1[i][1], bv0[j][1]);
      }
    __builtin_amdgcn_s_setprio(0);
    __builtin_amdgcn_s_barrier();
#pragma unroll
    for (int j = 0; j < FN - 2; ++j) { bv1[j][0] = rdB1(bufc, 2 + j, 0); bv1[j][1] = rdB1(bufc, 2 + j, 1); }
    stA(1, T + 2);
    __builtin_amdgcn_s_barrier();
    asm volatile("s_waitcnt lgkmcnt(0)" ::: "memory");
    __builtin_amdgcn_sched_barrier(0);
    __builtin_amdgcn_s_setprio(1);
#pragma unroll
    for (int i = 0; i < 4; ++i)
#pragma unroll
      for (int j = 0; j < FN - 2; ++j) {
        MFMA16(acc[i][2 + j], av0[i][0], bv1[j][0]);
        MFMA16(acc[i][2 + j], av0[i][1], bv1[j][1]);
      }
    __builtin_amdgcn_s_setprio(0);
    asm volatile("s_waitcnt vmcnt(6)" ::: "memory");
    __builtin_amdgcn_s_barrier();
  }
  __builtin_amdgcn_s_setprio(1);
#pragma unroll
  for (int i = 0; i < 4; ++i)
#pragma unroll
    for (int j = 0; j < FN - 2; ++j) {
      MFMA16(acc[4 + i][2 + j], av1[i][0], bv1[j][0]);
      MFMA16(acc[4 + i][2 + j], av1[i][1], bv1[j][1]);
    }
  __builtin_amdgcn_s_setprio(0);
  asm volatile("s_waitcnt vmcnt(0)" ::: "memory");
  __builtin_amdgcn_s_barrier();

#pragma unroll
  for (int i = 0; i < 8; ++i) {
#pragma unroll
    for (int j = 0; j < FN; ++j) {
      const int col = bn + wc * WCW + j * 16 + mr;
      float bb = 0.f;
      if (HASBIAS) bb = bias[col];
#pragma unroll
      for (int r = 0; r < 4; ++r) {
        const int row = bm + wr * 128 + i * 16 + quad * 4 + r;
        float v = acc[i][j][r];
        if (HASBIAS) v += bb;
        if (RELU) v = fmaxf(v, 0.f);
        if (EPI == 2)
          atomicAdd(&((float*)Cp)[(size_t)row * ldc + col], v);
        else if (EPI == 1)
          ((float*)Cp)[(size_t)zb * Mtot * ldc + (size_t)row * ldc + col] = v;
        else
          ((unsigned short*)Cp)[(size_t)row * ldc + col] = f2h(v);
      }
    }
  }
}

// ---------------------------------------------------------------------------
// qk256 v2: S = Q·K^T + exp + per-(row,128-col-tile) m/l stats.
// 256x128 tile, BK=32, 2 blocks/CU (LDS 48KB, regs<=128 via launch_bounds
// (512,4)). R7 pm: the 1-block/CU 256^2 kernel is structure-bound (28%
// MfmaUtil, ~1300cy dead time/phase, 4 serial rounds) — co-residency fills
// the barrier bubbles. 4-phase schedule mirrors the verified template incl.
// the stage-lag rule: region read@phX is staged@phX+1 (lgkm+barrier between);
// B staged opposite-parity.
// Ledger (3 stage units/tile: A0,Bf,A1; 1 load/thread each):
//   prologue A0(0),Bf(0),A1(0),A0(1),A1(1) -> vmcnt(2) = tile0 landed.
//   per tile: ph0 st Bf(T+1); ph1 st A0(T+2); ph3 st A1(T+2); vmcnt(2) at
//   ph3 end keeps {A0,A1}(T+2), drains Bf(T+1) + A0/A1(T+1) -> T+1 ready.
// Swizzle (64B rows = 4x16B slots): phys slot = slot ^ (row&3); stage
// pre-swizzles the GLOBAL col, reads XOR identically -> 2-way max (free).
// A halves: h covers rows {h*64+[0,64)} u {128+h*64+[0,64)} (read ph0/ph2);
//   LDS row-in-half p*64+rr <-> global row p*128+h*64+rr.
// B: identity, LDS row p <-> global row bn+p (full 128-row tile, 8KB).
// Stats: tile index = nb (64 tiles of 128 cols) — PV/combine_alpha unchanged.
// XCD map: nb = xcd*8 + (c&7), mb = c>>3 -> concurrent/XCD = 8 mb x 8 nb,
// K-panels (1.5MB) pinned per XCD, Q streams.
// ---------------------------------------------------------------------------
__global__ __launch_bounds__(512, 4) void qk256(
    const unsigned short* __restrict__ A, const unsigned short* __restrict__ B,
    unsigned short* __restrict__ P, float* __restrict__ stm,
    float* __restrict__ stl, int M, int K, int lda, int ldb, int ldc) {
  extern __shared__ char smem[];
  const int NT = K >> 5;           // BK=32
  constexpr int BUFSZ = 24576;     // A 16KB + B 8KB

  const int b = blockIdx.x;
  const int xcd = b & 7, c = b >> 3;
  const int mb = c >> 3;                   // 32 M-tiles
  const int nb = (xcd << 3) | (c & 7);     // 64 N-tiles, 8 per XCD
  const int bm = mb << 8, bn = nb << 7;

  const int tid = threadIdx.x;
  const int wave = tid >> 6, lane = tid & 63;
  const int wr = wave >> 2, wc = wave & 3;
  const int mr = lane & 15, quad = lane >> 4;

  const int rr2 = tid >> 2;                        // row-in-region 0..127
  const int ce = ((tid & 3) ^ (rr2 & 3)) << 3;     // pre-swizzled col (f16)
  const int arow = (rr2 >> 6) * 128 + (rr2 & 63);  // + h*64 for A halves

  f32x4 acc[8][2] = {};
  f16x8 av0[4], av1[4], bv0, bv1;

  auto stA = [&](int h, int Ts) {
    const int t = Ts >= NT ? Ts - NT : Ts;         // tail wrap keeps ledger
    const int kk = t << 5;
    char* l = smem + (Ts & 1) * BUFSZ + h * 8192 + wave * 1024;
    async_ld16(A + ((unsigned)(bm + arow + h * 64) * (unsigned)lda + kk + ce), l);
  };
  auto stB = [&](int Ts) {
    const int t = Ts >= NT ? Ts - NT : Ts;
    const int kk = t << 5;
    char* l = smem + (Ts & 1) * BUFSZ + 16384 + wave * 1024;
    async_ld16(B + ((unsigned)(bn + rr2) * (unsigned)ldb + kk + ce), l);
  };
  auto rdA = [&](int bufc, int i) {
    const int r = wr * 64 + (i & 3) * 16 + mr;     // r&3 == mr&3
    return *(const f16x8*)(smem + bufc + (i >> 2) * 8192 + r * 64 +
                           ((quad ^ (mr & 3)) << 4));
  };
  auto rdB = [&](int bufc, int j) {
    const int r = wc * 32 + j * 16 + mr;           // r&3 == mr&3
    return *(const f16x8*)(smem + bufc + 16384 + r * 64 +
                           ((quad ^ (mr & 3)) << 4));
  };

  // prologue: tile0 (A0,Bf,A1) + tile1 (A0,A1); Bf(1) staged at T=0 ph0
  stA(0, 0); stB(0); stA(1, 0); stA(0, 1); stA(1, 1);
  asm volatile("s_waitcnt vmcnt(2)" ::: "memory");
  __builtin_amdgcn_s_barrier();

  for (int T = 0; T < NT; ++T) {
    const int bufc = (T & 1) * BUFSZ;
    // ph0: rd av0 | st Bf(T+1) | MFMA prev acc[4..7][1]
#pragma unroll
    for (int i = 0; i < 4; ++i) av0[i] = rdA(bufc, i);
    stB(T + 1);
    __builtin_amdgcn_s_barrier();
    asm volatile("s_waitcnt lgkmcnt(0)" ::: "memory");
    __builtin_amdgcn_sched_barrier(0);
    if (T) {
      __builtin_amdgcn_s_setprio(1);
#pragma unroll
      for (int i = 0; i < 4; ++i) MFMA16(acc[4 + i][1], av1[i], bv1);
      __builtin_amdgcn_s_setprio(0);
    }
    __builtin_amdgcn_s_barrier();
    // ph1: rd bv0 | st A0(T+2) | MFMA acc[0..3][0]
    bv0 = rdB(bufc, 0);
    stA(0, T + 2);
    __builtin_amdgcn_s_barrier();
    asm volatile("s_waitcnt lgkmcnt(0)" ::: "memory");
    __builtin_amdgcn_sched_barrier(0);
    __builtin_amdgcn_s_setprio(1);
#pragma unroll
    for (int i = 0; i < 4; ++i) MFMA16(acc[i][0], av0[i], bv0);
    __builtin_amdgcn_s_setprio(0);
    __builtin_amdgcn_s_barrier();
    // ph2: rd av1 | MFMA acc[4..7][0]
#pragma unroll
    for (int i = 0; i < 4; ++i) av1[i] = rdA(bufc, 4 + i);
    __builtin_amdgcn_s_barrier();
    asm volatile("s_waitcnt lgkmcnt(0)" ::: "memory");
    __builtin_amdgcn_sched_barrier(0);
    __builtin_amdgcn_s_setprio(1);
#pragma unroll
    for (int i = 0; i < 4; ++i) MFMA16(acc[4 + i][0], av1[i], bv0);
    __builtin_amdgcn_s_setprio(0);
    __builtin_amdgcn_s_barrier();
    // ph3: rd bv1 | st A1(T+2) | MFMA acc[0..3][1] | vmcnt(2)
    bv1 = rdB(bufc, 1);
    stA(1, T + 2);
    __builtin_amdgcn_s_barrier();
    asm volatile("s_waitcnt lgkmcnt(0)" ::: "memory");
    __builtin_amdgcn_sched_barrier(0);
    __builtin_amdgcn_s_setprio(1);
#pragma unroll
    for (int i = 0; i < 4; ++i) MFMA16(acc[i][1], av0[i], bv1);
    __builtin_amdgcn_s_setprio(0);
    asm volatile("s_waitcnt vmcnt(2)" ::: "memory");
    __builtin_amdgcn_s_barrier();
  }
  // final cross-tile cluster
  __builtin_amdgcn_s_setprio(1);
#pragma unroll
  for (int i = 0; i < 4; ++i) MFMA16(acc[4 + i][1], av1[i], bv1);
  __builtin_amdgcn_s_setprio(0);
  asm volatile("s_waitcnt vmcnt(0)" ::: "memory");
  __builtin_amdgcn_s_barrier();

  // ---- epilogue: exp + per-(row, nb-tile) m/l stats ----------------------
  float* sred = (float*)smem;            // [256][4]
  float* ssum = (float*)(smem + 4096);   // [256][4]
  float Mh[8][4];

#pragma unroll
  for (int i = 0; i < 8; ++i)
#pragma unroll
    for (int r = 0; r < 4; ++r) {
      float m = fmaxf(acc[i][0][r], acc[i][1][r]);
      m = fmaxf(m, __shfl_xor(m, 1));
      m = fmaxf(m, __shfl_xor(m, 2));
      m = fmaxf(m, __shfl_xor(m, 4));
      m = fmaxf(m, __shfl_xor(m, 8));
      if (mr == 0) sred[(wr * 128 + i * 16 + quad * 4 + r) * 4 + wc] = m;
    }
  __syncthreads();
#pragma unroll
  for (int i = 0; i < 8; ++i)
#pragma unroll
    for (int r = 0; r < 4; ++r) {
      const int row_l = wr * 128 + i * 16 + quad * 4 + r;
      Mh[i][r] = fmaxf(fmaxf(sred[row_l * 4], sred[row_l * 4 + 1]),
                       fmaxf(sred[row_l * 4 + 2], sred[row_l * 4 + 3]));
    }
#pragma unroll
  for (int i = 0; i < 8; ++i)
#pragma unroll
    for (int r = 0; r < 4; ++r) {
      const int row_l = wr * 128 + i * 16 + quad * 4 + r;
      float l = 0.f;
#pragma unroll
      for (int j = 0; j < 2; ++j) {
        const float e = __expf(acc[i][j][r] - Mh[i][r]);
        P[(size_t)(bm + row_l) * ldc + (bn + wc * 32 + j * 16 + mr)] = f2h(e);
        l += e;
      }
      l += __shfl_xor(l, 1);
      l += __shfl_xor(l, 2);
      l += __shfl_xor(l, 4);
      l += __shfl_xor(l, 8);
      if (mr == 0) ssum[row_l * 4 + wc] = l;
    }
  __syncthreads();
  if (wc == 0 && mr == 0) {
#pragma unroll
    for (int i = 0; i < 8; ++i)
#pragma unroll
      for (int r = 0; r < 4; ++r) {
        const int row_l = wr * 128 + i * 16 + quad * 4 + r;
        stm[(size_t)nb * M + bm + row_l] = Mh[i][r];
        stl[(size_t)nb * M + bm + row_l] =
            ssum[row_l * 4] + ssum[row_l * 4 + 1] +
            ssum[row_l * 4 + 2] + ssum[row_l * 4 + 3];
      }
  }
}

// per-row combine: M = max_t m_t, L = sum_t l_t*exp(m_t-M)
__global__ __launch_bounds__(256) void combine_alpha(
    const float* __restrict__ stm, const float* __restrict__ stl,
    unsigned short* __restrict__ alp, int ntile, int Mtot) {
  const int row = blockIdx.x * 4 + (threadIdx.x >> 6);
  const int t = threadIdx.x & 63;
  float m = (t < ntile) ? stm[(size_t)t * Mtot + row] : -1e30f;
  float M = m;
#pragma unroll
  for (int o = 1; o < 64; o <<= 1) M = fmaxf(M, __shfl_xor(M, o));
  float l = (t < ntile) ? stl[(size_t)t * Mtot + row] : 0.f;
  float c = l * __expf(m - M);
#pragma unroll
  for (int o = 1; o < 64; o <<= 1) c += __shfl_xor(c, o);
  if (t < ntile) alp[(size_t)t * Mtot + row] = f2h(__expf(m - M) / c);
}

// merged fp32->fp16 conversion for Q, K, W1, W2 (vectorized x4)
__global__ __launch_bounds__(256) void prep4(
    const float* __restrict__ Q, const float* __restrict__ Km,
    const float* __restrict__ W1, const float* __restrict__ W2,
    unsigned short* __restrict__ qh, unsigned short* __restrict__ kh,
    unsigned short* __restrict__ w1h, unsigned short* __restrict__ w2h,
    int nqk4, int nw4) {
  int i = blockIdx.x * 256 + threadIdx.x;
  if (i >= 2 * nqk4 + 2 * nw4) return;
  const float* src;
  unsigned short* dst;
  int j = i;
  if (j < nqk4) { src = Q; dst = qh; }
  else if ((j -= nqk4) < nqk4) { src = Km; dst = kh; }
  else if ((j -= nqk4) < nw4) { src = W1; dst = w1h; }
  else { j -= nw4; src = W2; dst = w2h; }
  f32x4 v = ((const f32x4*)src)[j];
  us4 r;
#pragma unroll
  for (int k = 0; k < 4; ++k) r[k] = f2h(v[k]);
  ((us4*)dst)[j] = r;
}

// ctx16 = f2h(shardA + shardB)   (vectorized x4)
__global__ __launch_bounds__(256) void combine2_cvt(const f32x4* __restrict__ a,
                                                    const f32x4* __restrict__ b,
                                                    us4* __restrict__ o, int n4) {
  int i = blockIdx.x * 256 + threadIdx.x;
  if (i < n4) {
    f32x4 va = a[i], vb = b[i];
    us4 r;
#pragma unroll
    for (int j = 0; j < 4; ++j) r[j] = f2h(va[j] + vb[j]);
    o[i] = r;
  }
}

// out = shardA + shardB + bias[col]   (vectorized x4; d4 = D/4)
__global__ __launch_bounds__(256) void combine2_bias(const f32x4* __restrict__ a,
                                                     const f32x4* __restrict__ b,
                                                     const float* __restrict__ bias,
                                                     f32x4* __restrict__ o, int n4, int d4) {
  int i = blockIdx.x * 256 + threadIdx.x;
  if (i < n4) {
    f32x4 va = a[i], vb = b[i];
    const int c = (i % d4) * 4;
    f32x4 r;
#pragma unroll
    for (int j = 0; j < 4; ++j) r[j] = va[j] + vb[j] + bias[c + j];
    o[i] = r;
  }
}

// V [8192 x 768] fp32 -> vT [768 x 8192] fp16
__global__ __launch_bounds__(256) void vt_kernel(const float* __restrict__ V,
                                                 unsigned short* __restrict__ vT) {
  __shared__ float t[32][33];
  const int bx = blockIdx.x, by = blockIdx.y;
  const int x = threadIdx.x, y = threadIdx.y;
#pragma unroll
  for (int r = 0; r < 4; ++r)
    t[y + r * 8][x] = V[(size_t)(by * 32 + y + r * 8) * 768 + bx * 32 + x];
  __syncthreads();
#pragma unroll
  for (int r = 0; r < 4; ++r)
    vT[(size_t)(bx * 32 + y + r * 8) * 8192 + by * 32 + x] = f2h(t[x][y + r * 8]);
}

// ---------------------------------------------------------------------------
extern "C" void kernel_launch(void* const* d_in, const int* in_sizes, int n_in,
                              void* d_out, int out_size, void* d_ws, size_t ws_size,
                              hipStream_t stream) {
  const int N = 8192, D = 768, DFF = 2048;
  const float* Q  = (const float*)d_in[0];
  const float* Km = (const float*)d_in[1];
  const float* V  = (const float*)d_in[2];
  const float* W1 = (const float*)d_in[3];
  const float* b1 = (const float*)d_in[4];
  const float* W2 = (const float*)d_in[5];
  const float* b2 = (const float*)d_in[6];

  // Workspace layout — byte-identical to R7 (254.8 MB total).
  char* w = (char*)d_ws;
  size_t off = 0;
  auto take = [&](size_t bytes) { void* p = w + off; off += bytes; return p; };
  unsigned short* qh   = (unsigned short*)take((size_t)N * D * 2);
  unsigned short* kh   = (unsigned short*)take((size_t)N * D * 2);
  unsigned short* vT   = (unsigned short*)take((size_t)N * D * 2);
  unsigned short* ctx16= (unsigned short*)take((size_t)N * D * 2);
  float*          ctx32= (float*)take((size_t)N * D * 4);
  unsigned short* hb   = (unsigned short*)take((size_t)N * DFF * 2);
  unsigned short* w1h  = (unsigned short*)take((size_t)DFF * D * 2);
  unsigned short* w2h  = (unsigned short*)take((size_t)D * DFF * 2);
  float*          stm  = (float*)take((size_t)64 * N * 4);
  float*          stl  = (float*)take((size_t)64 * N * 4);
  unsigned short* alp  = (unsigned short*)take((size_t)64 * N * 2);  // [tile][row]
  unsigned short* Pp   = (unsigned short*)take((size_t)N * N * 2);   // P' fp16, 128 MB
  float* ctxsh = ctx32;          // PV shards x2 alias ctx32 + hb-head
  float* osh   = (float*)Pp;     // FFN2 shards x2 alias Pp (dead after PV)
  (void)ws_size;

  prep4<<<((2 * N * D + 2 * DFF * D) / 4 + 255) / 256, 256, 0, stream>>>(
      Q, Km, W1, W2, qh, kh, w1h, w2h, N * D / 4, DFF * D / 4);
  vt_kernel<<<dim3(D / 32, N / 32), dim3(32, 8), 0, stream>>>(V, vT);

  {  // QK^T 256x128 BK=32, 2 blocks/CU, fused exp + stats
    hipFuncSetAttribute((const void*)qk256,
                        hipFuncAttributeMaxDynamicSharedMemorySize, 49152);
    qk256<<<(N / 256) * (N / 128), 512, 49152, stream>>>(
        qh, kh, Pp, stm, stl, N, D, D, D, N);
  }
  combine_alpha<<<N / 4, 256, 0, stream>>>(stm, stl, alp, 64, N);

  {  // ctx shards = (alphaT .* P') . V — 256x192, sl=2, grid 256, shard store
    const int nt = D / 192, mt = N / 256, sl = 2;
    constexpr int BUFSZ = 32768 + 192 * 128;
    const int smem_sz = 2 * BUFSZ + ((N / 2) >> 7) * 256 * 2;  // 131072
    hipFuncSetAttribute((const void*)gemm256<192, 1, false, false, true, true>,
                        hipFuncAttributeMaxDynamicSharedMemorySize, smem_sz);
    gemm256<192, 1, false, false, true, true><<<nt * mt * sl, 512, smem_sz, stream>>>(
        Pp, vT, ctxsh, nullptr, alp, N,
        N / sl, N, N, D, nt, mt, sl);
  }
  combine2_cvt<<<(N * D / 4 + 255) / 256, 256, 0, stream>>>(
      (const f32x4*)ctxsh, (const f32x4*)(ctxsh + (size_t)N * D), (us4*)ctx16, N * D / 4);

  {  // h = relu(ctx . W1^T + b1)  fp16 — 256x256, grid 256
    const int nt = DFF / 256, mt = N / 256;
    hipFuncSetAttribute((const void*)gemm256<256, 0, true, true, false, true>,
                        hipFuncAttributeMaxDynamicSharedMemorySize, 131072);
    gemm256<256, 0, true, true, false, true><<<nt * mt, 512, 131072, stream>>>(
        ctx16, w1h, hb, b1, nullptr, N,
        D, D, D, DFF, nt, mt, 1);
  }
  {  // out shards = h . W2^T — 256x192, sl=2, grid 256, shard store into Pp
    const int nt = D / 192, mt = N / 256, sl = 2;
    constexpr int BUFSZ = 32768 + 192 * 128;
    hipFuncSetAttribute((const void*)gemm256<192, 1, false, false, false, true>,
                        hipFuncAttributeMaxDynamicSharedMemorySize, 2 * BUFSZ);
    gemm256<192, 1, false, false, false, true><<<nt * mt * sl, 512, 2 * BUFSZ, stream>>>(
        hb, w2h, osh, nullptr, nullptr, N,
        DFF / sl, DFF, DFF, D, nt, mt, sl);
  }
  combine2_bias<<<(N * D / 4 + 255) / 256, 256, 0, stream>>>(
      (const f32x4*)osh, (const f32x4*)(osh + (size_t)N * D), b2,
      (f32x4*)d_out, N * D / 4, D / 4);
}

// Round 9
// 578.723 us; speedup vs baseline: 1.2089x; 1.2089x over previous
//
#include <hip/hip_runtime.h>
#include <cstdint>
#include <cstddef>

#define DEV __device__ __forceinline__

typedef _Float16 f16;
typedef __attribute__((ext_vector_type(8))) _Float16 f16x8;
typedef __attribute__((ext_vector_type(4))) float f32x4;
typedef __attribute__((ext_vector_type(4))) unsigned short us4;

DEV unsigned short f2h(float f) {
  f16 h = (f16)f;
  return __builtin_bit_cast(unsigned short, h);
}

DEV void async_ld16(const void* g, void* l) {
  __builtin_amdgcn_global_load_lds(
      (__attribute__((address_space(1))) unsigned int*)(uintptr_t)g,
      (__attribute__((address_space(3))) unsigned int*)(uint32_t)(uintptr_t)l,
      16, 0, 0);
}

#define MFMA16(d, a, b_) (d) = __builtin_amdgcn_mfma_f32_16x16x32_f16((a), (b_), (d), 0, 0, 0)

// ---------------------------------------------------------------------------
// gemm256: C[M x N] = A[M x K] * B[N x K]^T  (K-contiguous, f16-as-ushort)
// 256xBN tile (BN in {256,192}), BK=64, 8 waves (2Mx4N), 8-phase pipeline
// (schedule verified R1-R3; BN=192 verified R5). Unchanged since R7.
// NOTE (R8 evidence): __launch_bounds__ 2nd arg = min BLOCKS per CU (CUDA
// semantics) in this toolchain — (512,2) -> 128-reg cap (VGPR_Count 124).
// EPI: 0 = fp16 store (+bias/relu), 1 = fp32 shard store at Cp + zb*Mtot*ldc,
//      2 = fp32 atomicAdd (legacy).
// ---------------------------------------------------------------------------
template <int BN, int EPI, bool RELU, bool HASBIAS, bool ALPHA, bool XCD>
__global__ __launch_bounds__(512, 2) void gemm256(
    const unsigned short* __restrict__ A, const unsigned short* __restrict__ B,
    void* __restrict__ Cp, const float* __restrict__ bias,
    const unsigned short* __restrict__ alp, int Mtot,
    int K, int lda, int ldb, int ldc, int nt, int mt, int sl) {
  extern __shared__ char smem[];
  constexpr int FN = BN / 64;
  constexpr int WCW = BN / 4;
  constexpr int BUFSZ = 32768 + BN * 128;
  const int NT = K >> 6;

  int mb, nb, zb;
  {
    const int b = blockIdx.x;
    if (XCD) {
      const int xcd = b & 7, q = b >> 3;
      nb = q % nt;
      const int rest = q / nt;
      zb = rest % sl;
      mb = xcd * (mt >> 3) + rest / sl;
    } else {
      nb = b % nt;
      const int t = b / nt;
      mb = t % mt;
      zb = t / mt;
    }
  }
  const int bm = mb << 8, bn = nb * BN;
  const unsigned koff = (unsigned)zb * (unsigned)K;

  const int tid = threadIdx.x;
  const int wave = tid >> 6, lane = tid & 63;
  const int wr = wave >> 2, wc = wave & 3;
  const int mr = lane & 15, quad = lane >> 4;

  const int slot = tid & 7, rr = tid >> 3;
  const int ce = (slot ^ (rr & 7)) << 3;

  f32x4 acc[8][FN] = {};
  f16x8 av0[4][2], av1[4][2], bv0[2][2], bv1[FN - 2][2];
  const f16* alb = (const f16*)(smem + 2 * BUFSZ);

  if (ALPHA) {
    const int ntl = K >> 7;
    const unsigned short* g0 = alp + (size_t)(zb * ntl) * Mtot + bm;
    uint4* s = (uint4*)(smem + 2 * BUFSZ);
    const int nu4 = (ntl << 5);
    for (int idx = tid; idx < nu4; idx += 512) {
      const int tt = idx >> 5;
      const int ru = (idx & 31) << 3;
      s[idx] = *(const uint4*)(g0 + (size_t)tt * Mtot + ru);
    }
  }

  auto stA = [&](int h, int Ts) {
    const int t_ = Ts >= NT ? Ts - NT : Ts;
    const unsigned kk = koff + (unsigned)(t_ << 6);
    char* l = smem + (Ts & 1) * BUFSZ + h * 16384 + wave * 1024;
#pragma unroll
    for (int p = 0; p < 2; ++p) {
      const unsigned off = (unsigned)(bm + p * 128 + h * 64 + rr) * (unsigned)lda + kk + ce;
      async_ld16(A + off, l + p * 8192);
    }
  };
  auto stB = [&](int h, int Ts) {
    const int t_ = Ts >= NT ? Ts - NT : Ts;
    const unsigned kk = koff + (unsigned)(t_ << 6);
    char* l = smem + (Ts & 1) * BUFSZ + 32768 + h * 16384 + wave * 1024;
    if (BN == 256) {
#pragma unroll
      for (int p = 0; p < 2; ++p) {
        const int g = bn + p * 128 + (rr >> 5) * 64 + h * 32 + (rr & 31);
        async_ld16(B + ((unsigned)g * (unsigned)ldb + kk + ce), l + p * 8192);
      }
    } else if (h == 0) {
#pragma unroll
      for (int p = 0; p < 2; ++p) {
        const int g = bn + (p * 2 + (rr >> 5)) * 48 + (rr & 31);
        async_ld16(B + ((unsigned)g * (unsigned)ldb + kk + ce), l + p * 8192);
      }
    } else {
      const int g = bn + (rr >> 4) * 48 + 32 + (rr & 15);
      async_ld16(B + ((unsigned)g * (unsigned)ldb + kk + ce), l);
    }
  };
  auto rdA = [&](int bufc, int i, int ks) {
    const int r = wr * 64 + (i & 3) * 16 + mr;
    return *(const f16x8*)(smem + bufc + (i >> 2) * 16384 + r * 128 +
                           ((((ks << 2) | quad) ^ (mr & 7)) << 4));
  };
  auto rdB0 = [&](int bufc, int j, int ks) {
    const int rb = wc * 32 + j * 16 + mr;
    return *(const f16x8*)(smem + bufc + 32768 + rb * 128 +
                           ((((ks << 2) | quad) ^ (mr & 7)) << 4));
  };
  auto rdB1 = [&](int bufc, int j, int ks) {
    const int rb = (BN == 256) ? (wc * 32 + (j - 2) * 16 + mr) : (wc * 16 + mr);
    return *(const f16x8*)(smem + bufc + 32768 + 16384 + rb * 128 +
                           ((((ks << 2) | quad) ^ (mr & 7)) << 4));
  };

  stA(0, 0); stB(0, 0); stA(1, 0); stB(1, 0);
  stA(0, 1); stB(0, 1); stA(1, 1);
  if (ALPHA) asm volatile("s_waitcnt lgkmcnt(0)" ::: "memory");
  asm volatile("s_waitcnt vmcnt(6)" ::: "memory");
  __builtin_amdgcn_s_barrier();

  for (int T = 0; T < NT; ++T) {
    const int bufc = (T & 1) * BUFSZ;
    f16 a0_[4], a1_[4];
#pragma unroll
    for (int i = 0; i < 4; ++i) { av0[i][0] = rdA(bufc, i, 0); av0[i][1] = rdA(bufc, i, 1); }
    if (ALPHA) {
#pragma unroll
      for (int i = 0; i < 4; ++i) a0_[i] = alb[(T >> 1) * 256 + wr * 128 + i * 16 + mr];
    }
    stB(1, T + 1);
    __builtin_amdgcn_s_barrier();
    asm volatile("s_waitcnt lgkmcnt(0)" ::: "memory");
    __builtin_amdgcn_sched_barrier(0);
    if (ALPHA) {
#pragma unroll
      for (int i = 0; i < 4; ++i) { av0[i][0] = av0[i][0] * a0_[i]; av0[i][1] = av0[i][1] * a0_[i]; }
    }
    if (T) {
      __builtin_amdgcn_s_setprio(1);
#pragma unroll
      for (int i = 0; i < 4; ++i)
#pragma unroll
        for (int j = 0; j < FN - 2; ++j) {
          MFMA16(acc[4 + i][2 + j], av1[i][0], bv1[j][0]);
          MFMA16(acc[4 + i][2 + j], av1[i][1], bv1[j][1]);
        }
      __builtin_amdgcn_s_setprio(0);
    }
    __builtin_amdgcn_s_barrier();
#pragma unroll
    for (int j = 0; j < 2; ++j) { bv0[j][0] = rdB0(bufc, j, 0); bv0[j][1] = rdB0(bufc, j, 1); }
    stA(0, T + 2);
    __builtin_amdgcn_s_barrier();
    asm volatile("s_waitcnt lgkmcnt(0)" ::: "memory");
    __builtin_amdgcn_sched_barrier(0);
    __builtin_amdgcn_s_setprio(1);
#pragma unroll
    for (int i = 0; i < 4; ++i)
#pragma unroll
      for (int j = 0; j < 2; ++j) {
        MFMA16(acc[i][j], av0[i][0], bv0[j][0]);
        MFMA16(acc[i][j], av0[i][1], bv0[j][1]);
      }
    __builtin_amdgcn_s_setprio(0);
    __builtin_amdgcn_s_barrier();
#pragma unroll
    for (int i = 0; i < 4; ++i) { av1[i][0] = rdA(bufc, 4 + i, 0); av1[i][1] = rdA(bufc, 4 + i, 1); }
    if (ALPHA) {
#pragma unroll
      for (int i = 0; i < 4; ++i) a1_[i] = alb[(T >> 1) * 256 + wr * 128 + 64 + i * 16 + mr];
    }
    stB(0, T + 2);
    __builtin_amdgcn_s_barrier();
    asm volatile("s_waitcnt lgkmcnt(0)" ::: "memory");
    __builtin_amdgcn_sched_barrier(0);
    if (ALPHA) {
#pragma unroll
      for (int i = 0; i < 4; ++i) { av1[i][0] = av1[i][0] * a1_[i]; av1[i][1] = av1[i][1] * a1_[i]; }
    }
    __builtin_amdgcn_s_setprio(1);
#pragma unroll
    for (int i = 0; i < 4; ++i)
#pragma unroll
      for (int j = 0; j < 2; ++j) {
        MFMA16(acc[4 + i][j], av1[i][0], bv0[j][0]);
        MFMA16(acc[4 + i][j], av1[i][1], bv0[j][1]);
      }
    __builtin_amdgcn_s_setprio(0);
    __builtin_amdgcn_s_barrier();
#pragma unroll
    for (int j = 0; j < FN - 2; ++j) { bv1[j][0] = rdB1(bufc, 2 + j, 0); bv1[j][1] = rdB1(bufc, 2 + j, 1); }
    stA(1, T + 2);
    __builtin_amdgcn_s_barrier();
    asm volatile("s_waitcnt lgkmcnt(0)" ::: "memory");
    __builtin_amdgcn_sched_barrier(0);
    __builtin_amdgcn_s_setprio(1);
#pragma unroll
    for (int i = 0; i < 4; ++i)
#pragma unroll
      for (int j = 0; j < FN - 2; ++j) {
        MFMA16(acc[i][2 + j], av0[i][0], bv1[j][0]);
        MFMA16(acc[i][2 + j], av0[i][1], bv1[j][1]);
      }
    __builtin_amdgcn_s_setprio(0);
    asm volatile("s_waitcnt vmcnt(6)" ::: "memory");
    __builtin_amdgcn_s_barrier();
  }
  __builtin_amdgcn_s_setprio(1);
#pragma unroll
  for (int i = 0; i < 4; ++i)
#pragma unroll
    for (int j = 0; j < FN - 2; ++j) {
      MFMA16(acc[4 + i][2 + j], av1[i][0], bv1[j][0]);
      MFMA16(acc[4 + i][2 + j], av1[i][1], bv1[j][1]);
    }
  __builtin_amdgcn_s_setprio(0);
  asm volatile("s_waitcnt vmcnt(0)" ::: "memory");
  __builtin_amdgcn_s_barrier();

#pragma unroll
  for (int i = 0; i < 8; ++i) {
#pragma unroll
    for (int j = 0; j < FN; ++j) {
      const int col = bn + wc * WCW + j * 16 + mr;
      float bb = 0.f;
      if (HASBIAS) bb = bias[col];
#pragma unroll
      for (int r = 0; r < 4; ++r) {
        const int row = bm + wr * 128 + i * 16 + quad * 4 + r;
        float v = acc[i][j][r];
        if (HASBIAS) v += bb;
        if (RELU) v = fmaxf(v, 0.f);
        if (EPI == 2)
          atomicAdd(&((float*)Cp)[(size_t)row * ldc + col], v);
        else if (EPI == 1)
          ((float*)Cp)[(size_t)zb * Mtot * ldc + (size_t)row * ldc + col] = v;
        else
          ((unsigned short*)Cp)[(size_t)row * ldc + col] = f2h(v);
      }
    }
  }
}

// ---------------------------------------------------------------------------
// qk256 v2.1: S = Q·K^T + exp + per-(row,128-col-tile) m/l stats.
// 256x128 tile, BK=32, target 2 blocks/CU. R8 post-mortem fixes:
//  (a) __launch_bounds__(512, 2): 2nd arg = min BLOCKS/CU (CUDA semantics;
//      R8's (512,4) -> 4-block budget -> 64-reg cap -> acc spill -> 530MB
//      scratch writes). (512,2) -> 128-reg cap; data regs = 104.
//  (b) swizzle extended to swz(r) = (r&3)^((r>>2)&3): R8's (r&3)-only left
//      quarter-wave rows {0,4,8,12} on one 4-bank group (1.57e7 conflicts);
//      with (b), each parity class covers each slot exactly 2x -> 2-way=free.
//      Read slot = quad ^ (mr&3) ^ ((mr>>2)&3) (row-terms reduce to mr-only
//      on both A and B paths); stage pre-swizzles the global col identically.
// Dataflow/ledger/epilogue byte-identical to R8 (correctness PASSED there).
// Ledger: prologue A0(0),Bf(0),A1(0),A0(1),A1(1) -> vmcnt(2); per tile
// stages ph0 Bf(T+1), ph1 A0(T+2), ph3 A1(T+2); vmcnt(2) at ph3 end.
// XCD map: nb = xcd*8 + (c&7), mb = c>>3 (K-panels L2-pinned per XCD).
// ---------------------------------------------------------------------------
__global__ __launch_bounds__(512, 2) void qk256(
    const unsigned short* __restrict__ A, const unsigned short* __restrict__ B,
    unsigned short* __restrict__ P, float* __restrict__ stm,
    float* __restrict__ stl, int M, int K, int lda, int ldb, int ldc) {
  extern __shared__ char smem[];
  const int NT = K >> 5;           // BK=32
  constexpr int BUFSZ = 24576;     // A 16KB + B 8KB

  const int b = blockIdx.x;
  const int xcd = b & 7, c = b >> 3;
  const int mb = c >> 3;                   // 32 M-tiles
  const int nb = (xcd << 3) | (c & 7);     // 64 N-tiles, 8 per XCD
  const int bm = mb << 8, bn = nb << 7;

  const int tid = threadIdx.x;
  const int wave = tid >> 6, lane = tid & 63;
  const int wr = wave >> 2, wc = wave & 3;
  const int mr = lane & 15, quad = lane >> 4;

  const int rr2 = tid >> 2;                        // row-in-region 0..127
  const int ce = ((tid & 3) ^ (rr2 & 3) ^ ((rr2 >> 2) & 3)) << 3;  // pre-swz col
  const int arow = (rr2 >> 6) * 128 + (rr2 & 63);  // + h*64 for A halves
  const int sw = (mr & 3) ^ ((mr >> 2) & 3);       // read-side swizzle term

  f32x4 acc[8][2] = {};
  f16x8 av0[4], av1[4], bv0, bv1;

  auto stA = [&](int h, int Ts) {
    const int t = Ts >= NT ? Ts - NT : Ts;         // tail wrap keeps ledger
    const int kk = t << 5;
    char* l = smem + (Ts & 1) * BUFSZ + h * 8192 + wave * 1024;
    async_ld16(A + ((unsigned)(bm + arow + h * 64) * (unsigned)lda + kk + ce), l);
  };
  auto stB = [&](int Ts) {
    const int t = Ts >= NT ? Ts - NT : Ts;
    const int kk = t << 5;
    char* l = smem + (Ts & 1) * BUFSZ + 16384 + wave * 1024;
    async_ld16(B + ((unsigned)(bn + rr2) * (unsigned)ldb + kk + ce), l);
  };
  auto rdA = [&](int bufc, int i) {
    const int r = wr * 64 + (i & 3) * 16 + mr;     // swz(r) == sw
    return *(const f16x8*)(smem + bufc + (i >> 2) * 8192 + r * 64 +
                           ((quad ^ sw) << 4));
  };
  auto rdB = [&](int bufc, int j) {
    const int r = wc * 32 + j * 16 + mr;           // swz(r) == sw
    return *(const f16x8*)(smem + bufc + 16384 + r * 64 +
                           ((quad ^ sw) << 4));
  };

  // prologue: tile0 (A0,Bf,A1) + tile1 (A0,A1); Bf(1) staged at T=0 ph0
  stA(0, 0); stB(0); stA(1, 0); stA(0, 1); stA(1, 1);
  asm volatile("s_waitcnt vmcnt(2)" ::: "memory");
  __builtin_amdgcn_s_barrier();

  for (int T = 0; T < NT; ++T) {
    const int bufc = (T & 1) * BUFSZ;
    // ph0: rd av0 | st Bf(T+1) | MFMA prev acc[4..7][1]
#pragma unroll
    for (int i = 0; i < 4; ++i) av0[i] = rdA(bufc, i);
    stB(T + 1);
    __builtin_amdgcn_s_barrier();
    asm volatile("s_waitcnt lgkmcnt(0)" ::: "memory");
    __builtin_amdgcn_sched_barrier(0);
    if (T) {
      __builtin_amdgcn_s_setprio(1);
#pragma unroll
      for (int i = 0; i < 4; ++i) MFMA16(acc[4 + i][1], av1[i], bv1);
      __builtin_amdgcn_s_setprio(0);
    }
    __builtin_amdgcn_s_barrier();
    // ph1: rd bv0 | st A0(T+2) | MFMA acc[0..3][0]
    bv0 = rdB(bufc, 0);
    stA(0, T + 2);
    __builtin_amdgcn_s_barrier();
    asm volatile("s_waitcnt lgkmcnt(0)" ::: "memory");
    __builtin_amdgcn_sched_barrier(0);
    __builtin_amdgcn_s_setprio(1);
#pragma unroll
    for (int i = 0; i < 4; ++i) MFMA16(acc[i][0], av0[i], bv0);
    __builtin_amdgcn_s_setprio(0);
    __builtin_amdgcn_s_barrier();
    // ph2: rd av1 | MFMA acc[4..7][0]
#pragma unroll
    for (int i = 0; i < 4; ++i) av1[i] = rdA(bufc, 4 + i);
    __builtin_amdgcn_s_barrier();
    asm volatile("s_waitcnt lgkmcnt(0)" ::: "memory");
    __builtin_amdgcn_sched_barrier(0);
    __builtin_amdgcn_s_setprio(1);
#pragma unroll
    for (int i = 0; i < 4; ++i) MFMA16(acc[4 + i][0], av1[i], bv0);
    __builtin_amdgcn_s_setprio(0);
    __builtin_amdgcn_s_barrier();
    // ph3: rd bv1 | st A1(T+2) | MFMA acc[0..3][1] | vmcnt(2)
    bv1 = rdB(bufc, 1);
    stA(1, T + 2);
    __builtin_amdgcn_s_barrier();
    asm volatile("s_waitcnt lgkmcnt(0)" ::: "memory");
    __builtin_amdgcn_sched_barrier(0);
    __builtin_amdgcn_s_setprio(1);
#pragma unroll
    for (int i = 0; i < 4; ++i) MFMA16(acc[i][1], av0[i], bv1);
    __builtin_amdgcn_s_setprio(0);
    asm volatile("s_waitcnt vmcnt(2)" ::: "memory");
    __builtin_amdgcn_s_barrier();
  }
  // final cross-tile cluster
  __builtin_amdgcn_s_setprio(1);
#pragma unroll
  for (int i = 0; i < 4; ++i) MFMA16(acc[4 + i][1], av1[i], bv1);
  __builtin_amdgcn_s_setprio(0);
  asm volatile("s_waitcnt vmcnt(0)" ::: "memory");
  __builtin_amdgcn_s_barrier();

  // ---- epilogue: exp + per-(row, nb-tile) m/l stats ----------------------
  float* sred = (float*)smem;            // [256][4]
  float* ssum = (float*)(smem + 4096);   // [256][4]
  float Mh[8][4];

#pragma unroll
  for (int i = 0; i < 8; ++i)
#pragma unroll
    for (int r = 0; r < 4; ++r) {
      float m = fmaxf(acc[i][0][r], acc[i][1][r]);
      m = fmaxf(m, __shfl_xor(m, 1));
      m = fmaxf(m, __shfl_xor(m, 2));
      m = fmaxf(m, __shfl_xor(m, 4));
      m = fmaxf(m, __shfl_xor(m, 8));
      if (mr == 0) sred[(wr * 128 + i * 16 + quad * 4 + r) * 4 + wc] = m;
    }
  __syncthreads();
#pragma unroll
  for (int i = 0; i < 8; ++i)
#pragma unroll
    for (int r = 0; r < 4; ++r) {
      const int row_l = wr * 128 + i * 16 + quad * 4 + r;
      Mh[i][r] = fmaxf(fmaxf(sred[row_l * 4], sred[row_l * 4 + 1]),
                       fmaxf(sred[row_l * 4 + 2], sred[row_l * 4 + 3]));
    }
#pragma unroll
  for (int i = 0; i < 8; ++i)
#pragma unroll
    for (int r = 0; r < 4; ++r) {
      const int row_l = wr * 128 + i * 16 + quad * 4 + r;
      float l = 0.f;
#pragma unroll
      for (int j = 0; j < 2; ++j) {
        const float e = __expf(acc[i][j][r] - Mh[i][r]);
        P[(size_t)(bm + row_l) * ldc + (bn + wc * 32 + j * 16 + mr)] = f2h(e);
        l += e;
      }
      l += __shfl_xor(l, 1);
      l += __shfl_xor(l, 2);
      l += __shfl_xor(l, 4);
      l += __shfl_xor(l, 8);
      if (mr == 0) ssum[row_l * 4 + wc] = l;
    }
  __syncthreads();
  if (wc == 0 && mr == 0) {
#pragma unroll
    for (int i = 0; i < 8; ++i)
#pragma unroll
      for (int r = 0; r < 4; ++r) {
        const int row_l = wr * 128 + i * 16 + quad * 4 + r;
        stm[(size_t)nb * M + bm + row_l] = Mh[i][r];
        stl[(size_t)nb * M + bm + row_l] =
            ssum[row_l * 4] + ssum[row_l * 4 + 1] +
            ssum[row_l * 4 + 2] + ssum[row_l * 4 + 3];
      }
  }
}

// per-row combine: M = max_t m_t, L = sum_t l_t*exp(m_t-M)
__global__ __launch_bounds__(256) void combine_alpha(
    const float* __restrict__ stm, const float* __restrict__ stl,
    unsigned short* __restrict__ alp, int ntile, int Mtot) {
  const int row = blockIdx.x * 4 + (threadIdx.x >> 6);
  const int t = threadIdx.x & 63;
  float m = (t < ntile) ? stm[(size_t)t * Mtot + row] : -1e30f;
  float M = m;
#pragma unroll
  for (int o = 1; o < 64; o <<= 1) M = fmaxf(M, __shfl_xor(M, o));
  float l = (t < ntile) ? stl[(size_t)t * Mtot + row] : 0.f;
  float c = l * __expf(m - M);
#pragma unroll
  for (int o = 1; o < 64; o <<= 1) c += __shfl_xor(c, o);
  if (t < ntile) alp[(size_t)t * Mtot + row] = f2h(__expf(m - M) / c);
}

// merged fp32->fp16 conversion for Q, K, W1, W2 (vectorized x4)
__global__ __launch_bounds__(256) void prep4(
    const float* __restrict__ Q, const float* __restrict__ Km,
    const float* __restrict__ W1, const float* __restrict__ W2,
    unsigned short* __restrict__ qh, unsigned short* __restrict__ kh,
    unsigned short* __restrict__ w1h, unsigned short* __restrict__ w2h,
    int nqk4, int nw4) {
  int i = blockIdx.x * 256 + threadIdx.x;
  if (i >= 2 * nqk4 + 2 * nw4) return;
  const float* src;
  unsigned short* dst;
  int j = i;
  if (j < nqk4) { src = Q; dst = qh; }
  else if ((j -= nqk4) < nqk4) { src = Km; dst = kh; }
  else if ((j -= nqk4) < nw4) { src = W1; dst = w1h; }
  else { j -= nw4; src = W2; dst = w2h; }
  f32x4 v = ((const f32x4*)src)[j];
  us4 r;
#pragma unroll
  for (int k = 0; k < 4; ++k) r[k] = f2h(v[k]);
  ((us4*)dst)[j] = r;
}

// ctx16 = f2h(shardA + shardB)   (vectorized x4)
__global__ __launch_bounds__(256) void combine2_cvt(const f32x4* __restrict__ a,
                                                    const f32x4* __restrict__ b,
                                                    us4* __restrict__ o, int n4) {
  int i = blockIdx.x * 256 + threadIdx.x;
  if (i < n4) {
    f32x4 va = a[i], vb = b[i];
    us4 r;
#pragma unroll
    for (int j = 0; j < 4; ++j) r[j] = f2h(va[j] + vb[j]);
    o[i] = r;
  }
}

// out = shardA + shardB + bias[col]   (vectorized x4; d4 = D/4)
__global__ __launch_bounds__(256) void combine2_bias(const f32x4* __restrict__ a,
                                                     const f32x4* __restrict__ b,
                                                     const float* __restrict__ bias,
                                                     f32x4* __restrict__ o, int n4, int d4) {
  int i = blockIdx.x * 256 + threadIdx.x;
  if (i < n4) {
    f32x4 va = a[i], vb = b[i];
    const int c = (i % d4) * 4;
    f32x4 r;
#pragma unroll
    for (int j = 0; j < 4; ++j) r[j] = va[j] + vb[j] + bias[c + j];
    o[i] = r;
  }
}

// V [8192 x 768] fp32 -> vT [768 x 8192] fp16
__global__ __launch_bounds__(256) void vt_kernel(const float* __restrict__ V,
                                                 unsigned short* __restrict__ vT) {
  __shared__ float t[32][33];
  const int bx = blockIdx.x, by = blockIdx.y;
  const int x = threadIdx.x, y = threadIdx.y;
#pragma unroll
  for (int r = 0; r < 4; ++r)
    t[y + r * 8][x] = V[(size_t)(by * 32 + y + r * 8) * 768 + bx * 32 + x];
  __syncthreads();
#pragma unroll
  for (int r = 0; r < 4; ++r)
    vT[(size_t)(bx * 32 + y + r * 8) * 8192 + by * 32 + x] = f2h(t[x][y + r * 8]);
}

// ---------------------------------------------------------------------------
extern "C" void kernel_launch(void* const* d_in, const int* in_sizes, int n_in,
                              void* d_out, int out_size, void* d_ws, size_t ws_size,
                              hipStream_t stream) {
  const int N = 8192, D = 768, DFF = 2048;
  const float* Q  = (const float*)d_in[0];
  const float* Km = (const float*)d_in[1];
  const float* V  = (const float*)d_in[2];
  const float* W1 = (const float*)d_in[3];
  const float* b1 = (const float*)d_in[4];
  const float* W2 = (const float*)d_in[5];
  const float* b2 = (const float*)d_in[6];

  // Workspace layout — byte-identical to R7 (254.8 MB total).
  char* w = (char*)d_ws;
  size_t off = 0;
  auto take = [&](size_t bytes) { void* p = w + off; off += bytes; return p; };
  unsigned short* qh   = (unsigned short*)take((size_t)N * D * 2);
  unsigned short* kh   = (unsigned short*)take((size_t)N * D * 2);
  unsigned short* vT   = (unsigned short*)take((size_t)N * D * 2);
  unsigned short* ctx16= (unsigned short*)take((size_t)N * D * 2);
  float*          ctx32= (float*)take((size_t)N * D * 4);
  unsigned short* hb   = (unsigned short*)take((size_t)N * DFF * 2);
  unsigned short* w1h  = (unsigned short*)take((size_t)DFF * D * 2);
  unsigned short* w2h  = (unsigned short*)take((size_t)D * DFF * 2);
  float*          stm  = (float*)take((size_t)64 * N * 4);
  float*          stl  = (float*)take((size_t)64 * N * 4);
  unsigned short* alp  = (unsigned short*)take((size_t)64 * N * 2);  // [tile][row]
  unsigned short* Pp   = (unsigned short*)take((size_t)N * N * 2);   // P' fp16, 128 MB
  float* ctxsh = ctx32;          // PV shards x2 alias ctx32 + hb-head
  float* osh   = (float*)Pp;     // FFN2 shards x2 alias Pp (dead after PV)
  (void)ws_size;

  prep4<<<((2 * N * D + 2 * DFF * D) / 4 + 255) / 256, 256, 0, stream>>>(
      Q, Km, W1, W2, qh, kh, w1h, w2h, N * D / 4, DFF * D / 4);
  vt_kernel<<<dim3(D / 32, N / 32), dim3(32, 8), 0, stream>>>(V, vT);

  {  // QK^T 256x128 BK=32, 2 blocks/CU, fused exp + stats
    hipFuncSetAttribute((const void*)qk256,
                        hipFuncAttributeMaxDynamicSharedMemorySize, 49152);
    qk256<<<(N / 256) * (N / 128), 512, 49152, stream>>>(
        qh, kh, Pp, stm, stl, N, D, D, D, N);
  }
  combine_alpha<<<N / 4, 256, 0, stream>>>(stm, stl, alp, 64, N);

  {  // ctx shards = (alphaT .* P') . V — 256x192, sl=2, grid 256, shard store
    const int nt = D / 192, mt = N / 256, sl = 2;
    constexpr int BUFSZ = 32768 + 192 * 128;
    const int smem_sz = 2 * BUFSZ + ((N / 2) >> 7) * 256 * 2;  // 131072
    hipFuncSetAttribute((const void*)gemm256<192, 1, false, false, true, true>,
                        hipFuncAttributeMaxDynamicSharedMemorySize, smem_sz);
    gemm256<192, 1, false, false, true, true><<<nt * mt * sl, 512, smem_sz, stream>>>(
        Pp, vT, ctxsh, nullptr, alp, N,
        N / sl, N, N, D, nt, mt, sl);
  }
  combine2_cvt<<<(N * D / 4 + 255) / 256, 256, 0, stream>>>(
      (const f32x4*)ctxsh, (const f32x4*)(ctxsh + (size_t)N * D), (us4*)ctx16, N * D / 4);

  {  // h = relu(ctx . W1^T + b1)  fp16 — 256x256, grid 256
    const int nt = DFF / 256, mt = N / 256;
    hipFuncSetAttribute((const void*)gemm256<256, 0, true, true, false, true>,
                        hipFuncAttributeMaxDynamicSharedMemorySize, 131072);
    gemm256<256, 0, true, true, false, true><<<nt * mt, 512, 131072, stream>>>(
        ctx16, w1h, hb, b1, nullptr, N,
        D, D, D, DFF, nt, mt, 1);
  }
  {  // out shards = h . W2^T — 256x192, sl=2, grid 256, shard store into Pp
    const int nt = D / 192, mt = N / 256, sl = 2;
    constexpr int BUFSZ = 32768 + 192 * 128;
    hipFuncSetAttribute((const void*)gemm256<192, 1, false, false, false, true>,
                        hipFuncAttributeMaxDynamicSharedMemorySize, 2 * BUFSZ);
    gemm256<192, 1, false, false, false, true><<<nt * mt * sl, 512, 2 * BUFSZ, stream>>>(
        hb, w2h, osh, nullptr, nullptr, N,
        DFF / sl, DFF, DFF, D, nt, mt, sl);
  }
  combine2_bias<<<(N * D / 4 + 255) / 256, 256, 0, stream>>>(
      (const f32x4*)osh, (const f32x4*)(osh + (size_t)N * D), b2,
      (f32x4*)d_out, N * D / 4, D / 4);
}